// Round 2
// baseline (4375.441 us; speedup 1.0000x reference)
//
#include <hip/hip_runtime.h>
#include <math.h>

// TransformerBlock1: b=4, DIM=192, h=256, w=192, HEADS=8, HID=768
#define SSP   49152   // h*w
#define HDIM  256
#define WDIM  192
#define CDIM  192
#define NHEAD 8
#define CH    24      // CDIM/NHEAD
#define OC3   576
#define HIDF  768
#define NB    4

// ---------------- LayerNorm over channel axis, one batch, layout [c][s] ----------------
__global__ __launch_bounds__(256) void ln_chan_1b(const float* __restrict__ x,
                                                  const float* __restrict__ w,
                                                  const float* __restrict__ bia,
                                                  float* __restrict__ y) {
  int s = blockIdx.x * 256 + threadIdx.x;   // 0..SSP-1
  float sum = 0.f, sumsq = 0.f;
  for (int c = 0; c < CDIM; ++c) {
    float v = x[(size_t)c * SSP + s];
    sum += v; sumsq += v * v;
  }
  float mu = sum * (1.f / CDIM);
  float var = sumsq * (1.f / CDIM) - mu * mu;
  float rstd = rsqrtf(var + 1e-5f);
  for (int c = 0; c < CDIM; ++c) {
    float v = x[(size_t)c * SSP + s];
    y[(size_t)c * SSP + s] = (v - mu) * rstd * w[c] + bia[c];
  }
}

// ---------------- 64x64x16 register-tiled fp32 GEMM ----------------
// C[m][n] = sum_k A[m][k]*B(k,n) (+bias[n]) (gelu) (+resid[m][n])
// B_TRANS=false: B is [K][N]. B_TRANS=true: B is [N][K].
// Requires M%64==0, N%64==0, K%16==0 (all call sites satisfy).
template <bool B_TRANS, bool BIAS, bool GELU, bool RESID>
__global__ __launch_bounds__(256) void gemm_tile(
    const float* __restrict__ A, const float* __restrict__ B,
    const float* __restrict__ bias, const float* __restrict__ resid,
    float* __restrict__ C, int M, int N, int K) {
  const int tid = threadIdx.x;
  const int bn = blockIdx.x, bm = blockIdx.y;

  __shared__ float As[16][64];
  __shared__ float Bs[16][64];

  const int lm = tid >> 2;          // 0..63
  const int lk = (tid & 3) * 4;     // 0,4,8,12
  const int ty = tid >> 4, tx = tid & 15;
  const int m0 = bm * 64, n0 = bn * 64;

  float acc[4][4] = {};

  for (int k0 = 0; k0 < K; k0 += 16) {
    float4 av = *(const float4*)(A + (size_t)(m0 + lm) * K + k0 + lk);
    As[lk + 0][lm] = av.x; As[lk + 1][lm] = av.y;
    As[lk + 2][lm] = av.z; As[lk + 3][lm] = av.w;
    if (B_TRANS) {
      float4 bv = *(const float4*)(B + (size_t)(n0 + lm) * K + k0 + lk);
      Bs[lk + 0][lm] = bv.x; Bs[lk + 1][lm] = bv.y;
      Bs[lk + 2][lm] = bv.z; Bs[lk + 3][lm] = bv.w;
    } else {
      const int bk = tid >> 4;            // 0..15
      const int bn4 = (tid & 15) * 4;     // 0..60
      float4 bv = *(const float4*)(B + (size_t)(k0 + bk) * N + n0 + bn4);
      *(float4*)&Bs[bk][bn4] = bv;
    }
    __syncthreads();
#pragma unroll
    for (int kk = 0; kk < 16; ++kk) {
      float4 a4 = *(const float4*)&As[kk][ty * 4];
      float4 b4 = *(const float4*)&Bs[kk][tx * 4];
      float ar[4] = {a4.x, a4.y, a4.z, a4.w};
      float br[4] = {b4.x, b4.y, b4.z, b4.w};
#pragma unroll
      for (int i = 0; i < 4; ++i)
#pragma unroll
        for (int j = 0; j < 4; ++j) acc[i][j] += ar[i] * br[j];
    }
    __syncthreads();
  }

#pragma unroll
  for (int i = 0; i < 4; ++i) {
    int m = m0 + ty * 4 + i;
#pragma unroll
    for (int j = 0; j < 4; ++j) {
      int n = n0 + tx * 4 + j;
      float v = acc[i][j];
      if (BIAS) v += bias[n];
      if (GELU) v = 0.5f * v * (1.f + erff(v * 0.70710678118654752f));
      size_t idx = (size_t)m * N + n;
      if (RESID) v += resid[idx];
      C[idx] = v;
    }
  }
}

// ---------------- 3x3 depthwise conv, SAME padding, nchan channels, layout [o][y][x] ----------------
__global__ __launch_bounds__(256) void dwconv3(const float* __restrict__ in,
                                               const float* __restrict__ w9,
                                               float* __restrict__ out, int nchan) {
  int gid = blockIdx.x * 256 + threadIdx.x;   // over nchan*SSP (<= 9.44M)
  int s = gid % SSP;
  int o = gid / SSP;
  int y = s / WDIM, x = s - y * WDIM;
  const float* ip = in + (size_t)o * SSP;
  const float* wp = w9 + o * 9;
  float acc = 0.f;
#pragma unroll
  for (int dy = 0; dy < 3; ++dy) {
    int yy = y + dy - 1;
    if (yy < 0 || yy >= HDIM) continue;
#pragma unroll
    for (int dx = 0; dx < 3; ++dx) {
      int xx = x + dx - 1;
      if (xx < 0 || xx >= WDIM) continue;
      acc += wp[dy * 3 + dx] * ip[(size_t)yy * WDIM + xx];
    }
  }
  out[gid] = acc;
}

// ---------------- in-place L2 norm over spatial axis (q,k channels: 384 rows) ----------------
__global__ __launch_bounds__(256) void l2norm_rows(float* __restrict__ qk) {
  int cc = blockIdx.x;                // 0..383
  float* p = qk + (size_t)cc * SSP;
  int tid = threadIdx.x;
  float ss = 0.f;
  for (int n = tid; n < SSP; n += 256) { float v = p[n]; ss += v * v; }
#pragma unroll
  for (int off = 32; off; off >>= 1) ss += __shfl_xor(ss, off);
  __shared__ float w4[4];
  if ((tid & 63) == 0) w4[tid >> 6] = ss;
  __syncthreads();
  float tot = w4[0] + w4[1] + w4[2] + w4[3];
  float scale = 1.f / fmaxf(sqrtf(tot), 1e-12f);
  for (int n = tid; n < SSP; n += 256) p[n] *= scale;
}

// ---------------- attention scores + softmax (one batch): attn[h][c][d] ----------------
__global__ __launch_bounds__(256) void attn_scores_1b(const float* __restrict__ qk,
                                                      const float* __restrict__ temp,
                                                      float* __restrict__ attn) {
  int c = blockIdx.x;       // 0..23
  int h = blockIdx.y;       // 0..7
  const float* qrow = qk + (size_t)(h * CH + c) * SSP;
  const float* kb   = qk + (size_t)(CDIM + h * CH) * SSP;
  int tid = threadIdx.x;
  float acc[CH];
#pragma unroll
  for (int d = 0; d < CH; ++d) acc[d] = 0.f;
  for (int n = tid; n < SSP; n += 256) {
    float qv = qrow[n];
#pragma unroll
    for (int d = 0; d < CH; ++d) acc[d] += qv * kb[(size_t)d * SSP + n];
  }
#pragma unroll
  for (int d = 0; d < CH; ++d)
#pragma unroll
    for (int off = 32; off; off >>= 1) acc[d] += __shfl_xor(acc[d], off);
  __shared__ float wsum[4][CH];
  __shared__ float row[CH];
  int wave = tid >> 6, lane = tid & 63;
  if (lane == 0)
    for (int d = 0; d < CH; ++d) wsum[wave][d] = acc[d];
  __syncthreads();
  if (tid < CH)
    row[tid] = (wsum[0][tid] + wsum[1][tid] + wsum[2][tid] + wsum[3][tid]) * temp[h];
  __syncthreads();
  if (tid < CH) {
    float mx = -1e30f;
    for (int d = 0; d < CH; ++d) mx = fmaxf(mx, row[d]);
    float sum = 0.f;
    for (int d = 0; d < CH; ++d) sum += expf(row[d] - mx);
    float e = expf(row[tid] - mx);
    attn[(size_t)h * (CH * CH) + c * CH + tid] = e / sum;
  }
}

// ---------------- PV (one batch): out[h*24+c][n] = sum_d attn[h][c][d]*v[d][n] ----------------
__global__ __launch_bounds__(256) void attn_pv_1b(const float* __restrict__ qk,
                                                  const float* __restrict__ attn,
                                                  float* __restrict__ out) {
  int nb = blockIdx.x;      // 0..191
  int h = blockIdx.y;       // 0..7
  __shared__ float aL[CH][CH];
  int tid = threadIdx.x;
  for (int i = tid; i < CH * CH; i += 256) aL[i / CH][i % CH] = attn[(size_t)h * CH * CH + i];
  __syncthreads();
  int n = nb * 256 + tid;
  const float* vb = qk + (size_t)(2 * CDIM + h * CH) * SSP + n;
  float vv[CH];
#pragma unroll
  for (int d = 0; d < CH; ++d) vv[d] = vb[(size_t)d * SSP];
  float* ob = out + (size_t)(h * CH) * SSP + n;
#pragma unroll
  for (int cc = 0; cc < CH; ++cc) {
    float s = 0.f;
#pragma unroll
    for (int d = 0; d < CH; ++d) s += aL[cc][d] * vv[d];
    ob[(size_t)cc * SSP] = s;
  }
}

extern "C" void kernel_launch(void* const* d_in, const int* in_sizes, int n_in,
                              void* d_out, int out_size, void* d_ws, size_t ws_size,
                              hipStream_t stream) {
  const float* x      = (const float*)d_in[0];
  const float* ln1_w  = (const float*)d_in[1];
  const float* ln1_b  = (const float*)d_in[2];
  const float* temp   = (const float*)d_in[3];
  const float* qkv_w  = (const float*)d_in[4];
  const float* dw_w   = (const float*)d_in[5];
  const float* proj_w = (const float*)d_in[6];
  const float* ln2_w  = (const float*)d_in[7];
  const float* ln2_b  = (const float*)d_in[8];
  const float* fc1_w  = (const float*)d_in[9];
  const float* fc1_b  = (const float*)d_in[10];
  const float* fc2_w  = (const float*)d_in[11];
  const float* fc2_b  = (const float*)d_in[12];
  float* out = (float*)d_out;

  // Per-batch workspace, total 6*BSZ + 4608 floats ~= 216 MB
  const size_t BSZ = (size_t)CDIM * SSP;  // 9,437,184 floats
  float* ws  = (float*)d_ws;
  float* A   = ws;             // [0,1)BSZ : y1_b, later pv_b
  float* T   = ws + BSZ;       // [1,2)BSZ : qkv-part tmp, later y2_b
  float* D   = ws + 2 * BSZ;   // [2,5)BSZ : q|k|v after dwconv
  float* H   = ws + 2 * BSZ;   // [2,6)BSZ : h1 chunk (D dead by then)
  float* atn = ws + 6 * BSZ;   // 4608 floats

  for (int b = 0; b < NB; ++b) {
    const float* xb = x + (size_t)b * BSZ;
    float* outb = out + (size_t)b * BSZ;

    // 1. LN1: xb -> A
    ln_chan_1b<<<dim3(SSP / 256), dim3(256), 0, stream>>>(xb, ln1_w, ln1_b, A);
    // 2. qkv parts (q,k,v) GEMM + depthwise conv into D
    for (int p = 0; p < 3; ++p) {
      gemm_tile<false, false, false, false><<<dim3(SSP / 64, CDIM / 64), dim3(256), 0, stream>>>(
          qkv_w + (size_t)p * CDIM * CDIM, A, nullptr, nullptr, T, CDIM, SSP, CDIM);
      dwconv3<<<dim3(CDIM * SSP / 256), dim3(256), 0, stream>>>(
          T, dw_w + p * CDIM * 9, D + (size_t)p * BSZ, CDIM);
    }
    // 3. l2norm q,k rows in place
    l2norm_rows<<<dim3(2 * CDIM), dim3(256), 0, stream>>>(D);
    // 4. scores + softmax
    attn_scores_1b<<<dim3(CH, NHEAD), dim3(256), 0, stream>>>(D, temp, atn);
    // 5. PV -> A
    attn_pv_1b<<<dim3(SSP / 256, NHEAD), dim3(256), 0, stream>>>(D, atn, A);
    // 6. x1_b = proj_w @ pv + xb -> outb (x1 lives in d_out)
    gemm_tile<false, false, false, true><<<dim3(SSP / 64, CDIM / 64), dim3(256), 0, stream>>>(
        proj_w, A, nullptr, xb, outb, CDIM, SSP, CDIM);
    // 7. LN2: outb -> T (y2_b)
    ln_chan_1b<<<dim3(SSP / 256), dim3(256), 0, stream>>>(outb, ln2_w, ln2_b, T);
    // 8. h1_b = gelu(y2_b @ fc1^T + b1): M=49152,N=768,K=192
    gemm_tile<true, true, true, false><<<dim3(HIDF / 64, SSP / 64), dim3(256), 0, stream>>>(
        T, fc1_w, fc1_b, nullptr, H, SSP, HIDF, CDIM);
    // 9. outb = h1_b @ fc2^T + b2 + outb(x1): M=49152,N=192,K=768 (in-place resid, same-idx)
    gemm_tile<true, true, false, true><<<dim3(CDIM / 64, SSP / 64), dim3(256), 0, stream>>>(
        H, fc2_w, fc2_b, outb, outb, SSP, CDIM, HIDF);
  }
}

// Round 3
// 2059.418 us; speedup vs baseline: 2.1246x; 2.1246x over previous
//
#include <hip/hip_runtime.h>
#include <math.h>

// TransformerBlock1: b=4, DIM=192, h=256, w=192, HEADS=8, HID=768
#define SSP   49152   // h*w
#define HDIM  256
#define WDIM  192
#define CDIM  192
#define NHEAD 8
#define CH    24
#define OC3   576
#define HIDF  768
#define NB    4
#define SCCH  24      // score chunks (each block covers SSP/24 = 2048 positions)

typedef short bf16x8 __attribute__((ext_vector_type(8)));
typedef float f32x4  __attribute__((ext_vector_type(4)));

__device__ inline short f2bf(float f) {   // RNE f32 -> bf16 bit pattern
  unsigned int u = __float_as_uint(f);
  u += 0x7fffu + ((u >> 16) & 1u);
  return (short)(u >> 16);
}

// ---------------- f32 -> bf16 bulk convert (weights) ----------------
__global__ __launch_bounds__(256) void cvt_bf16(const float* __restrict__ in,
                                                short* __restrict__ out, int n) {
  int i = blockIdx.x * 256 + threadIdx.x;
  if (i < n) out[i] = f2bf(in[i]);
}

// ---------------- LN over channels -> bf16 TRANSPOSED [s][192] ----------------
__global__ __launch_bounds__(256) void ln_to_bf16T(const float* __restrict__ x,
                                                   const float* __restrict__ w,
                                                   const float* __restrict__ b,
                                                   short* __restrict__ yt) {
  int s = blockIdx.x * 256 + threadIdx.x;
  float sum = 0.f, sq = 0.f;
  for (int c = 0; c < CDIM; ++c) {
    float v = x[(size_t)c * SSP + s];
    sum += v; sq += v * v;
  }
  float mu = sum * (1.f / CDIM);
  float rstd = rsqrtf(sq * (1.f / CDIM) - mu * mu + 1e-5f);
  short* yp = yt + (size_t)s * CDIM;
  for (int c8 = 0; c8 < CDIM / 8; ++c8) {
    bf16x8 v;
#pragma unroll
    for (int j = 0; j < 8; ++j) {
      int c = c8 * 8 + j;
      v[j] = f2bf((x[(size_t)c * SSP + s] - mu) * rstd * w[c] + b[c]);
    }
    *(bf16x8*)(yp + c8 * 8) = v;
  }
}

// ---------------- LN over channels -> bf16 NATURAL [c][s] ----------------
__global__ __launch_bounds__(256) void ln_to_bf16N(const float* __restrict__ x,
                                                   const float* __restrict__ w,
                                                   const float* __restrict__ b,
                                                   short* __restrict__ y) {
  int s = blockIdx.x * 256 + threadIdx.x;
  float sum = 0.f, sq = 0.f;
  for (int c = 0; c < CDIM; ++c) {
    float v = x[(size_t)c * SSP + s];
    sum += v; sq += v * v;
  }
  float mu = sum * (1.f / CDIM);
  float rstd = rsqrtf(sq * (1.f / CDIM) - mu * mu + 1e-5f);
  for (int c = 0; c < CDIM; ++c) {
    float v = x[(size_t)c * SSP + s];
    y[(size_t)c * SSP + s] = f2bf((v - mu) * rstd * w[c] + b[c]);
  }
}

// ---------------- MFMA bf16 GEMM, NT: A[M][K], B[N][K], both K-contiguous ----------------
// C[m][n] = sum_k A[m][k]*B[n][k] (+bias[n]) (gelu) (+resid) ; out fp32 or bf16
template <int BM, int BN, int WM, int WN, bool BIAS, bool GELU, bool RESID, bool OUT_BF16>
__global__ __launch_bounds__(256) void mfma_gemm(
    const short* __restrict__ A, const short* __restrict__ B,
    const float* __restrict__ bias, const float* __restrict__ resid,
    void* __restrict__ Cv, int M, int N, int K) {
  constexpr int BK = 32, PAD = 40;
  constexpr int WTM = BM / WM, WTN = BN / WN;
  constexpr int FM = WTM / 16, FN = WTN / 16;
  static_assert(WM * WN == 4 && BM % 64 == 0 && BN % 64 == 0, "cfg");
  __shared__ short As[BM * PAD];
  __shared__ short Bs[BN * PAD];
  const int tid = threadIdx.x;
  const int m0 = blockIdx.y * BM, n0 = blockIdx.x * BN;
  const int w = tid >> 6, lane = tid & 63;
  const int wm = w / WN, wn = w % WN;
  const int r16 = lane & 15, kg = lane >> 4;
  const int arow = tid >> 2, akc = tid & 3;   // staging: row, 8-elem k-chunk

  f32x4 acc[FM][FN] = {};

  for (int k0 = 0; k0 < K; k0 += BK) {
#pragma unroll
    for (int i = 0; i < BM; i += 64) {
      bf16x8 v = *(const bf16x8*)(A + (size_t)(m0 + i + arow) * K + k0 + akc * 8);
      *(bf16x8*)(&As[(i + arow) * PAD + akc * 8]) = v;
    }
#pragma unroll
    for (int i = 0; i < BN; i += 64) {
      bf16x8 v = *(const bf16x8*)(B + (size_t)(n0 + i + arow) * K + k0 + akc * 8);
      *(bf16x8*)(&Bs[(i + arow) * PAD + akc * 8]) = v;
    }
    __syncthreads();
    bf16x8 af[FM], bfr[FN];
#pragma unroll
    for (int i = 0; i < FM; ++i)
      af[i] = *(bf16x8*)(&As[(wm * WTM + i * 16 + r16) * PAD + kg * 8]);
#pragma unroll
    for (int j = 0; j < FN; ++j)
      bfr[j] = *(bf16x8*)(&Bs[(wn * WTN + j * 16 + r16) * PAD + kg * 8]);
#pragma unroll
    for (int i = 0; i < FM; ++i)
#pragma unroll
      for (int j = 0; j < FN; ++j)
        acc[i][j] = __builtin_amdgcn_mfma_f32_16x16x32_bf16(af[i], bfr[j], acc[i][j], 0, 0, 0);
    __syncthreads();
  }

  float* Cf = (float*)Cv;
  short* Ch = (short*)Cv;
#pragma unroll
  for (int i = 0; i < FM; ++i) {
#pragma unroll
    for (int j = 0; j < FN; ++j) {
#pragma unroll
      for (int t = 0; t < 4; ++t) {
        int m = m0 + wm * WTM + i * 16 + kg * 4 + t;
        int n = n0 + wn * WTN + j * 16 + r16;
        float v = acc[i][j][t];
        if (BIAS) v += bias[n];
        if (GELU) v = 0.5f * v * (1.f + erff(v * 0.70710678118654752f));
        size_t idx = (size_t)m * N + n;
        if (RESID) v += resid[idx];
        if (OUT_BF16) Ch[idx] = f2bf(v); else Cf[idx] = v;
      }
    }
  }
}

// ---------------- 3x3 depthwise conv, SAME, layout [o][y][x] (192 ch) ----------------
__global__ __launch_bounds__(256) void dwconv3(const float* __restrict__ in,
                                               const float* __restrict__ w9,
                                               float* __restrict__ out) {
  int gid = blockIdx.x * 256 + threadIdx.x;
  int s = gid % SSP;
  int o = gid / SSP;
  int y = s / WDIM, x = s - y * WDIM;
  const float* ip = in + (size_t)o * SSP;
  const float* wp = w9 + o * 9;
  float acc = 0.f;
#pragma unroll
  for (int dy = 0; dy < 3; ++dy) {
    int yy = y + dy - 1;
    if (yy < 0 || yy >= HDIM) continue;
#pragma unroll
    for (int dx = 0; dx < 3; ++dx) {
      int xx = x + dx - 1;
      if (xx < 0 || xx >= WDIM) continue;
      acc += wp[dy * 3 + dx] * ip[(size_t)yy * WDIM + xx];
    }
  }
  out[gid] = acc;
}

// ---------------- inverse L2 norms for q,k rows (384 rows of D) ----------------
__global__ __launch_bounds__(256) void rownorms(const float* __restrict__ D,
                                                float* __restrict__ rn) {
  int cc = blockIdx.x;
  const float* p = D + (size_t)cc * SSP;
  int tid = threadIdx.x;
  float ss = 0.f;
  for (int n = tid * 4; n < SSP; n += 1024) {
    float4 v = *(const float4*)(p + n);
    ss += v.x * v.x + v.y * v.y + v.z * v.z + v.w * v.w;
  }
#pragma unroll
  for (int off = 32; off; off >>= 1) ss += __shfl_xor(ss, off);
  __shared__ float w4[4];
  if ((tid & 63) == 0) w4[tid >> 6] = ss;
  __syncthreads();
  if (tid == 0)
    rn[cc] = 1.f / fmaxf(sqrtf(w4[0] + w4[1] + w4[2] + w4[3]), 1e-12f);
}

// ---------------- scores stage1: partial raw dots over 2048-pos chunks ----------------
__global__ __launch_bounds__(256) void scores_stage1(const float* __restrict__ D,
                                                     float* __restrict__ partial) {
  int ch = blockIdx.x;   // 0..23
  int h  = blockIdx.y;   // 0..7
  __shared__ float qs[24][260];
  __shared__ float ks[24][260];
  int tid = threadIdx.x;
  int w = tid >> 6, lane = tid & 63;
  int c0 = w * 6;
  float acc[6] = {0.f, 0.f, 0.f, 0.f, 0.f, 0.f};
  const float* qb = D + (size_t)(h * CH) * SSP;
  const float* kb = D + (size_t)(CDIM + h * CH) * SSP;
  for (int it = 0; it < 8; ++it) {
    int s0 = ch * 2048 + it * 256;
#pragma unroll
    for (int t = 0; t < 6; ++t) {
      int idx = t * 256 + tid;          // 0..1535
      int row = idx >> 6, col4 = (idx & 63) * 4;
      *(float4*)&qs[row][col4] = *(const float4*)(qb + (size_t)row * SSP + s0 + col4);
      *(float4*)&ks[row][col4] = *(const float4*)(kb + (size_t)row * SSP + s0 + col4);
    }
    __syncthreads();
    if (lane < 24) {
      for (int s = 0; s < 256; s += 4) {
        float4 kv = *(float4*)&ks[lane][s];
#pragma unroll
        for (int i = 0; i < 6; ++i) {
          float4 qv = *(float4*)&qs[c0 + i][s];
          acc[i] += qv.x * kv.x + qv.y * kv.y + qv.z * kv.z + qv.w * kv.w;
        }
      }
    }
    __syncthreads();
  }
  if (lane < 24) {
#pragma unroll
    for (int i = 0; i < 6; ++i)
      partial[(((size_t)h * CH + (c0 + i)) * CH + lane) * SCCH + ch] = acc[i];
  }
}

// ---------------- scores reduce + l2-norm scaling + temperature + softmax ----------------
__global__ void scores_reduce(const float* __restrict__ partial,
                              const float* __restrict__ rn,
                              const float* __restrict__ temp,
                              float* __restrict__ atn) {
  int c = blockIdx.x, h = blockIdx.y;
  int tid = threadIdx.x;   // 64
  __shared__ float row[24];
  if (tid < 24) {
    const float* p = partial + (((size_t)h * CH + c) * CH + tid) * SCCH;
    float s = 0.f;
#pragma unroll
    for (int i = 0; i < SCCH; ++i) s += p[i];
    row[tid] = s * rn[h * CH + c] * rn[CDIM + h * CH + tid] * temp[h];
  }
  __syncthreads();
  if (tid < 24) {
    float mx = -1e30f;
    for (int d = 0; d < 24; ++d) mx = fmaxf(mx, row[d]);
    float sum = 0.f;
    for (int d = 0; d < 24; ++d) sum += expf(row[d] - mx);
    atn[((size_t)h * CH + c) * CH + tid] = expf(row[tid] - mx) / sum;
  }
}

// ---------------- PV -> pvt bf16 [s][192] ----------------
__global__ __launch_bounds__(256) void attn_pv_bf16(const float* __restrict__ D,
                                                    const float* __restrict__ atn,
                                                    short* __restrict__ pvt) {
  int nb = blockIdx.x, h = blockIdx.y;
  __shared__ float aL[24][24];
  int tid = threadIdx.x;
  for (int i = tid; i < 576; i += 256) aL[i / 24][i % 24] = atn[(size_t)h * 576 + i];
  __syncthreads();
  int n = nb * 256 + tid;
  const float* vb = D + (size_t)(2 * CDIM + h * CH) * SSP + n;
  float vv[24];
#pragma unroll
  for (int d = 0; d < 24; ++d) vv[d] = vb[(size_t)d * SSP];
  short* ob = pvt + (size_t)n * CDIM + h * CH;
  bf16x8 o0, o1, o2;
#pragma unroll
  for (int cc = 0; cc < 24; ++cc) {
    float s = 0.f;
#pragma unroll
    for (int d = 0; d < 24; ++d) s += aL[cc][d] * vv[d];
    short bv = f2bf(s);
    if (cc < 8) o0[cc & 7] = bv; else if (cc < 16) o1[cc & 7] = bv; else o2[cc & 7] = bv;
  }
  *(bf16x8*)(ob) = o0;
  *(bf16x8*)(ob + 8) = o1;
  *(bf16x8*)(ob + 16) = o2;
}

extern "C" void kernel_launch(void* const* d_in, const int* in_sizes, int n_in,
                              void* d_out, int out_size, void* d_ws, size_t ws_size,
                              hipStream_t stream) {
  const float* x      = (const float*)d_in[0];
  const float* ln1_w  = (const float*)d_in[1];
  const float* ln1_b  = (const float*)d_in[2];
  const float* temp   = (const float*)d_in[3];
  const float* qkv_w  = (const float*)d_in[4];
  const float* dw_w   = (const float*)d_in[5];
  const float* proj_w = (const float*)d_in[6];
  const float* ln2_w  = (const float*)d_in[7];
  const float* ln2_b  = (const float*)d_in[8];
  const float* fc1_w  = (const float*)d_in[9];
  const float* fc1_b  = (const float*)d_in[10];
  const float* fc2_w  = (const float*)d_in[11];
  const float* fc2_b  = (const float*)d_in[12];
  float* out = (float*)d_out;

  const size_t BSZ = (size_t)CDIM * SSP;   // 9,437,184
  float* ws = (float*)d_ws;
  // float-unit offsets (total ~171 MB, well under proven ws capacity)
  short* wq   = (short*)(ws);                 // qkv_w bf16  (110592 sh = 55296 f)
  short* wp   = (short*)(ws + 55296);         // proj_w bf16 (36864 sh)
  short* w1   = (short*)(ws + 73728);         // fc1_w bf16  (147456 sh)
  short* w2   = (short*)(ws + 147456);        // fc2_w bf16  (147456 sh)
  float* atn  = ws + 262144;                  // 4608 f
  float* rn   = ws + 266752;                  // 384 f
  float* part = ws + 267136;                  // 110592 f
  short* y1t  = (short*)(ws + 393216);        // bf16 [SSP][192]; later pvt
  float* T    = ws + 5111808;                 // fp32 [192][SSP]; later y2 bf16
  float* D    = ws + 14548992;                // fp32 [576][SSP]; later h1 bf16
  short* pvt  = y1t;
  short* y2   = (short*)T;
  short* h1   = (short*)D;

  // weights -> bf16 (once per launch)
  cvt_bf16<<<dim3((110592 + 255) / 256), 256, 0, stream>>>(qkv_w, wq, 110592);
  cvt_bf16<<<dim3((36864 + 255) / 256), 256, 0, stream>>>(proj_w, wp, 36864);
  cvt_bf16<<<dim3((147456 + 255) / 256), 256, 0, stream>>>(fc1_w, w1, 147456);
  cvt_bf16<<<dim3((147456 + 255) / 256), 256, 0, stream>>>(fc2_w, w2, 147456);

  for (int b = 0; b < NB; ++b) {
    const float* xb = x + (size_t)b * BSZ;
    float* outb = out + (size_t)b * BSZ;

    // 1. LN1 -> y1t bf16 [s][192]
    ln_to_bf16T<<<dim3(SSP / 256), 256, 0, stream>>>(xb, ln1_w, ln1_b, y1t);
    // 2. qkv parts: GEMM (M=192,N=SSP,K=192) -> T fp32, then dwconv -> D
    for (int p = 0; p < 3; ++p) {
      mfma_gemm<64, 256, 1, 4, false, false, false, false>
          <<<dim3(SSP / 256, 192 / 64), 256, 0, stream>>>(
              wq + (size_t)p * CDIM * CDIM, y1t, nullptr, nullptr, T, CDIM, SSP, CDIM);
      dwconv3<<<dim3(CDIM * SSP / 256), 256, 0, stream>>>(T, dw_w + p * CDIM * 9,
                                                          D + (size_t)p * BSZ);
    }
    // 3. inverse L2 norms of q,k rows
    rownorms<<<dim3(2 * CDIM), 256, 0, stream>>>(D, rn);
    // 4. scores: partial dots, then reduce+scale+softmax
    scores_stage1<<<dim3(SCCH, NHEAD), 256, 0, stream>>>(D, part);
    scores_reduce<<<dim3(CH, NHEAD), 64, 0, stream>>>(part, rn, temp, atn);
    // 5. PV -> pvt bf16 [s][192]
    attn_pv_bf16<<<dim3(SSP / 256, NHEAD), 256, 0, stream>>>(D, atn, pvt);
    // 6. proj + residual x -> outb fp32 (M=192,N=SSP,K=192)
    mfma_gemm<64, 256, 1, 4, false, false, true, false>
        <<<dim3(SSP / 256, 192 / 64), 256, 0, stream>>>(
            wp, pvt, nullptr, xb, outb, CDIM, SSP, CDIM);
    // 7. LN2 -> y2 bf16 [c][s] (== rows of 192 w-elements)
    ln_to_bf16N<<<dim3(SSP / 256), 256, 0, stream>>>(outb, ln2_w, ln2_b, y2);
    // 8. fc1: (M=49152,N=768,K=192) + bias + gelu -> h1 bf16
    mfma_gemm<128, 128, 2, 2, true, true, false, true>
        <<<dim3(HIDF / 128, SSP / 128), 256, 0, stream>>>(
            y2, w1, fc1_b, nullptr, h1, SSP, HIDF, CDIM);
    // 9. fc2: (M=49152,N=192,K=768) + bias + residual(outb) -> outb
    mfma_gemm<128, 64, 2, 2, true, false, true, false>
        <<<dim3(CDIM / 64, SSP / 128), 256, 0, stream>>>(
            h1, w2, fc2_b, outb, outb, SSP, CDIM, HIDF);
  }
}